// Round 17
// baseline (251.920 us; speedup 1.0000x reference)
//
#include <hip/hip_runtime.h>
#include <hip/hip_bf16.h>
#include <cstdint>
#include <cstddef>

// Problem constants
#define NB   64
#define NS   8
#define DIM  2048
#define FF   4096
#define NE   8
#define TOK  512            // NB*NS
#define NPAIR 1024          // TOK*2

// GEMM tiling
#define BM   192            // 4 M-waves x 48 rows
#define BKE  32             // K per epoch (ffn2)
#define BK1  64             // K per epoch (ffn1: 2 MFMA slices per barrier)
#define ASZ  (BM * 4 * 8)   // shorts per ffn2 A LDS buffer (12 KB)
#define ASZ1 (BM * 8 * 8)   // shorts per ffn1 A LDS buffer (24 KB)

typedef __attribute__((ext_vector_type(4))) float f32x4;
typedef __attribute__((ext_vector_type(8))) short bf16x8;

#define MFMA16(a, b, c) __builtin_amdgcn_mfma_f32_16x16x32_bf16((a), (b), (c), 0, 0, 0)
#define SCHEDBAR __builtin_amdgcn_sched_barrier(0)
// barrier draining LDS only — vmcnt prefetches stay in flight across it
#define LGKMBAR do { asm volatile("s_waitcnt lgkmcnt(0)" ::: "memory"); \
                     asm volatile("s_barrier" ::: "memory");            \
                     __builtin_amdgcn_sched_barrier(0); } while (0)

// round-half-up fp32 -> bf16 (0.5 ulp)
static __device__ __forceinline__ short f2bf(float f) {
    unsigned u = __builtin_bit_cast(unsigned, f);
    return (short)((u + 0x8000u) >> 16);
}
// packed fp32x2 -> bf16x2 (RNE), 1 instruction
static __device__ __forceinline__ unsigned cvtpk(float lo, float hi) {
    unsigned r;
    asm("v_cvt_pk_bf16_f32 %0, %1, %2" : "=v"(r) : "v"(lo), "v"(hi));
    return r;
}
static __device__ __forceinline__ bf16x8 pack8(const float* v) {
    uint4 u;
    u.x = cvtpk(v[0], v[1]); u.y = cvtpk(v[2], v[3]);
    u.z = cvtpk(v[4], v[5]); u.w = cvtpk(v[6], v[7]);
    return __builtin_bit_cast(bf16x8, u);
}

static __device__ __forceinline__ void async16(void* l, const void* g) {
    __builtin_amdgcn_global_load_lds(
        (const __attribute__((address_space(1))) void*)g,
        (__attribute__((address_space(3))) void*)l, 16, 0, 0);
}

// ---------------------------------------------------------------------------
// Kernel 1: gating + x -> bf16 preconvert.
// ---------------------------------------------------------------------------
__global__ void gate_topk(const float* __restrict__ x, const float* __restrict__ gw,
                          unsigned short* __restrict__ xbf,
                          int* __restrict__ tok_expert, float* __restrict__ tok_gatew) {
    int token = blockIdx.x;
    int lane  = threadIdx.x;
    const float* xr = x + (size_t)token * DIM;

    float acc[NE];
#pragma unroll
    for (int e = 0; e < NE; ++e) acc[e] = 0.f;

    for (int d0 = lane * 8; d0 < DIM; d0 += 64 * 8) {
        float4 xa = *(const float4*)(xr + d0);
        float4 xb = *(const float4*)(xr + d0 + 4);
        bf16x8 v;
        v[0] = f2bf(xa.x); v[1] = f2bf(xa.y); v[2] = f2bf(xa.z); v[3] = f2bf(xa.w);
        v[4] = f2bf(xb.x); v[5] = f2bf(xb.y); v[6] = f2bf(xb.z); v[7] = f2bf(xb.w);
        *(bf16x8*)(xbf + (size_t)token * DIM + d0) = v;
#pragma unroll
        for (int j = 0; j < 8; ++j) {
            float xv = (j < 4) ? ((const float*)&xa)[j] : ((const float*)&xb)[j - 4];
            const float4* g = (const float4*)(gw + (size_t)(d0 + j) * NE);
            float4 g0 = g[0], g1 = g[1];
            acc[0] += xv * g0.x; acc[1] += xv * g0.y;
            acc[2] += xv * g0.z; acc[3] += xv * g0.w;
            acc[4] += xv * g1.x; acc[5] += xv * g1.y;
            acc[6] += xv * g1.z; acc[7] += xv * g1.w;
        }
    }
#pragma unroll
    for (int off = 32; off >= 1; off >>= 1) {
#pragma unroll
        for (int e = 0; e < NE; ++e) acc[e] += __shfl_down(acc[e], off);
    }
    if (lane == 0) {
        float b1 = -1e30f, b2 = -1e30f; int i1 = 0, i2 = 0;
#pragma unroll
        for (int e = 0; e < NE; ++e) {
            float v = acc[e];
            if (v > b1) { b2 = b1; i2 = i1; b1 = v; i1 = e; }
            else if (v > b2) { b2 = v; i2 = e; }
        }
        float t = __expf(b2 - b1);
        tok_expert[token * 2 + 0] = i1;
        tok_expert[token * 2 + 1] = i2;
        tok_gatew[token * 2 + 0] = 1.f / (1.f + t);
        tok_gatew[token * 2 + 1] = t / (1.f + t);
    }
}

// ---------------------------------------------------------------------------
// Kernel 2: deterministic per-expert token lists
// ---------------------------------------------------------------------------
__global__ void build_lists(const int* __restrict__ tok_expert,
                            const float* __restrict__ tok_gatew,
                            int* __restrict__ counts, int* __restrict__ offsets,
                            int* __restrict__ row_token, float* __restrict__ row_gatew,
                            int* __restrict__ pair_row) {
    __shared__ int s_off[NE];
    __shared__ int s_cnt[NE];
    int e    = threadIdx.x >> 6;
    int lane = threadIdx.x & 63;
    unsigned long long lt = (1ull << lane) - 1ull;

    int cnt = 0;
    for (int base = 0; base < NPAIR; base += 64) {
        int id = tok_expert[base + lane];
        unsigned long long m = __ballot(id == e);
        cnt += __popcll(m);
    }
    if (lane == 0) s_cnt[e] = cnt;
    __syncthreads();
    if (threadIdx.x == 0) {
        int o = 0;
        for (int i = 0; i < NE; ++i) {
            int c = s_cnt[i];
            counts[i] = c; offsets[i] = o; s_off[i] = o; o += c;
        }
    }
    __syncthreads();

    int rbase = s_off[e];
    for (int base = 0; base < NPAIR; base += 64) {
        int entry = base + lane;
        int id = tok_expert[entry];
        bool match = (id == e);
        unsigned long long m = __ballot(match);
        int pre = __popcll(m & lt);
        if (match) {
            int row = rbase + pre;
            row_token[row] = entry >> 1;
            row_gatew[row] = tok_gatew[entry];
            pair_row[entry] = row;
        }
        rbase += __popcll(m);
    }
}

// ---------------------------------------------------------------------------
// Kernel 3: H = silu(Xbf*w1) .* (Xbf*w3).  BKE=64: 32 epochs (half the
// barriers of R13).  grid = 256 (bid = tile*8 + e, XCD-pinned), 1024 thr =
// 4M x 4N waves, BN=128.  R13 pipeline: A DMA triple-buffer (distance-2,
// retirement implicit via next epoch's pack8(B) register wait); B reg-stage
// distance-2 (16 fp32/thread/epoch).  No explicit vmcnt; lgkm-only barrier.
// A swizzle for 128B rows: LDS chunk (m,c) holds src chunk (c-(m&7))&7;
// read position ((sl*4+lg)+(r&7))&7  -> 2-way (free).
// ---------------------------------------------------------------------------
#define EP1(RD, WR, BSR, BSW, PACKV, LOADV, S, HAS_P, HAS_W) do {           \
    if (HAS_P) {                                                            \
        async16(&(WR)[(size_t)t * 8], asrc0 + ((S) + 2) * BK1);             \
        if (t < 512)                                                        \
            async16(&(WR)[(size_t)(1024 + t) * 8], asrc1 + ((S) + 2) * BK1);\
    }                                                                       \
    SCHEDBAR;                                                               \
    if (HAS_P) {                                                            \
        _Pragma("unroll")                                                   \
        for (int u = 0; u < 16; ++u) {                                      \
            int sl_ = u >> 3, j_ = u & 7;                                   \
            LOADV[u] = bsrc[(size_t)(((S) + 2) * BK1 + sl_ * 32 + j_) * FF];\
        }                                                                   \
    }                                                                       \
    SCHEDBAR;                                                               \
    _Pragma("unroll")                                                       \
    for (int sl = 0; sl < 2; ++sl) {                                        \
        bf16x8 a_[3];                                                       \
        _Pragma("unroll")                                                   \
        for (int f = 0; f < 3; ++f) {                                       \
            int r_ = wm * 48 + f * 16 + l15;                                \
            int p_ = ((sl * 4 + lg) + (r_ & 7)) & 7;                        \
            a_[f] = *(const bf16x8*)&(RD)[((size_t)r_ * 8 + p_) * 8];       \
        }                                                                   \
        _Pragma("unroll")                                                   \
        for (int nf = 0; nf < 2; ++nf) {                                    \
            int ch_ = wn * 32 + nf * 16 + l15 + lg * 128;                   \
            bf16x8 b1f = *(const bf16x8*)&Bs[BSR][0][sl][ch_][0];           \
            bf16x8 b3f = *(const bf16x8*)&Bs[BSR][1][sl][ch_][0];           \
            _Pragma("unroll")                                               \
            for (int f = 0; f < 3; ++f) {                                   \
                acc1[f][nf] = MFMA16(a_[f], b1f, acc1[f][nf]);              \
                acc3[f][nf] = MFMA16(a_[f], b3f, acc3[f][nf]);              \
            }                                                               \
        }                                                                   \
    }                                                                       \
    if (HAS_W) {                                                            \
        bf16x8 wv0 = pack8(PACKV);                                          \
        bf16x8 wv1 = pack8(PACKV + 8);                                      \
        *(bf16x8*)&Bs[BSW][bmat][0][bch][0] = wv0;                          \
        *(bf16x8*)&Bs[BSW][bmat][1][bch][0] = wv1;                          \
    }                                                                       \
    LGKMBAR;                                                                \
} while (0)

__global__ __launch_bounds__(1024, 4) void ffn1(
    const unsigned short* __restrict__ xbf, const float* __restrict__ w1,
    const float* __restrict__ w3,
    const int* __restrict__ counts, const int* __restrict__ offsets,
    const int* __restrict__ row_token, unsigned short* __restrict__ Hbuf) {
    __shared__ __align__(16) unsigned short As[3 * ASZ1];          // 72 KB
    __shared__ __align__(16) unsigned short Bs[2][2][2][512][8];   // 64 KB

    int bid = blockIdx.x;
    int e  = bid & 7;                    // expert -> XCD (round-robin dispatch)
    int f0 = (bid >> 3) * 128;

    int Me = counts[e];
    if (Me == 0) return;
    int off = offsets[e];

    int t = threadIdx.x;
    int lane = t & 63;
    int w = t >> 6;
    int wm = w >> 2, wn = w & 3;         // 4 M-waves x 4 N-waves
    int l15 = lane & 15, lg = lane >> 4;

    const float* w1e = w1 + (size_t)e * DIM * FF + f0;
    const float* w3e = w3 + (size_t)e * DIM * FF + f0;

    // B role: one frag-chunk per slice (16 k-strided fp32) per thread/epoch
    int bmat = t >> 9;
    int bc   = t & 511;
    int bcol = bc & 127, blg = bc >> 7;
    const float* bsrc = (bmat ? w3e : w1e) + (size_t)(blg * 8) * FF + bcol;
    int bch = bcol + blg * 128;

    const int NST = DIM / BK1;           // 32 epochs

    for (int mb = 0; mb < Me; mb += BM) {
        __syncthreads();
        // A DMA sources: 1536 chunks; chunk i -> (m=i>>3, c=i&7); source
        // chunk (c-(m&7))&7 of row m.
        const unsigned short* asrc0;
        const unsigned short* asrc1;
        {
            int m0 = t >> 3, c0 = t & 7;
            int rl0 = mb + m0;
            int tok0 = row_token[off + ((rl0 < Me) ? rl0 : (Me - 1))];
            asrc0 = xbf + (size_t)tok0 * DIM + (((c0 - (m0 & 7)) & 7) << 3);
            int i1 = 1024 + t;
            int m1 = i1 >> 3, c1 = i1 & 7;
            int rl1 = mb + m1;
            int tok1 = row_token[off + ((rl1 < Me) ? rl1 : (Me - 1))];
            asrc1 = xbf + (size_t)tok1 * DIM + (((c1 - (m1 & 7)) & 7) << 3);
        }

        f32x4 acc1[3][2], acc3[3][2];
#pragma unroll
        for (int f = 0; f < 3; ++f)
#pragma unroll
            for (int nf = 0; nf < 2; ++nf) {
                acc1[f][nf] = (f32x4){0.f, 0.f, 0.f, 0.f};
                acc3[f][nf] = (f32x4){0.f, 0.f, 0.f, 0.f};
            }

        unsigned short* pRd = As;
        unsigned short* pMd = As + ASZ1;
        unsigned short* pWr = As + 2 * ASZ1;

        float bX[16], bY[16];

        // prologue: DMA(0)->pRd, DMA(1)->pMd; B(0)->bX->Bs[0] (pack-wait
        // retires the DMAs, one-time); B(1)->bY
        async16(&pRd[(size_t)t * 8], asrc0);
        if (t < 512) async16(&pRd[(size_t)(1024 + t) * 8], asrc1);
        async16(&pMd[(size_t)t * 8], asrc0 + BK1);
        if (t < 512) async16(&pMd[(size_t)(1024 + t) * 8], asrc1 + BK1);
        SCHEDBAR;
#pragma unroll
        for (int u = 0; u < 16; ++u) {
            int sl_ = u >> 3, j_ = u & 7;
            bX[u] = bsrc[(size_t)(sl_ * 32 + j_) * FF];
        }
        {
            bf16x8 wv0 = pack8(bX);
            bf16x8 wv1 = pack8(bX + 8);
            *(bf16x8*)&Bs[0][bmat][0][bch][0] = wv0;
            *(bf16x8*)&Bs[0][bmat][1][bch][0] = wv1;
        }
#pragma unroll
        for (int u = 0; u < 16; ++u) {
            int sl_ = u >> 3, j_ = u & 7;
            bY[u] = bsrc[(size_t)(BK1 + sl_ * 32 + j_) * FF];
        }
        LGKMBAR;

        for (int s = 0; s < NST - 2; s += 2) {
            EP1(pRd, pWr, 0, 1, bY, bX, s,     1, 1);
            EP1(pMd, pRd, 1, 0, bX, bY, s + 1, 1, 1);
            unsigned short* tt = pRd; pRd = pWr; pWr = pMd; pMd = tt;
        }
        EP1(pRd, pWr, 0, 1, bY, bX, NST - 2, 0, 1);
        EP1(pMd, pRd, 1, 0, bX, bY, NST - 1, 0, 0);

        // epilogue: silu(a1)*a3 -> bf16 H
#pragma unroll
        for (int f = 0; f < 3; ++f)
#pragma unroll
            for (int nf = 0; nf < 2; ++nf)
#pragma unroll
                for (int r = 0; r < 4; ++r) {
                    int rl = mb + wm * 48 + f * 16 + lg * 4 + r;
                    if (rl < Me) {
                        float a1 = acc1[f][nf][r], a3 = acc3[f][nf][r];
                        float h = (a1 / (1.f + __expf(-a1))) * a3;
                        Hbuf[(size_t)(off + rl) * FF + f0 + wn * 32 + nf * 16 + l15] =
                            (unsigned short)f2bf(h);
                    }
                }
    }
}

// ---------------------------------------------------------------------------
// Kernel 4 (= R14): OutPair partial = (H @ w2[K-half]) * gate_weight.
// K-SPLIT x2: grid = 512 (bid = (tile*2+ks)*8 + e), 2 blocks/CU.
// ---------------------------------------------------------------------------
#define EP2(RD, WR, BSR, BSW, PACKV, LOADV, S, HAS_P, HAS_W) do {           \
    if (HAS_P) {                                                            \
        async16(&(WR)[(size_t)t * 8], asrc0 + ((S) + 2) * BKE);             \
        if (t < 256)                                                        \
            async16(&(WR)[(size_t)(512 + t) * 8], asrc1 + ((S) + 2) * BKE); \
    }                                                                       \
    SCHEDBAR;                                                               \
    if (HAS_P) {                                                            \
        _Pragma("unroll")                                                   \
        for (int j = 0; j < 4; ++j)                                         \
            LOADV[j] = bsrc[(size_t)(((S) + 2) * BKE + j) * DIM];           \
    }                                                                       \
    SCHEDBAR;                                                               \
    bf16x8 a_[3];                                                           \
    _Pragma("unroll")                                                       \
    for (int f = 0; f < 3; ++f) {                                           \
        int r_ = wm * 48 + f * 16 + l15;                                    \
        int p_ = (lg + (r_ >> 1)) & 3;                                      \
        a_[f] = *(const bf16x8*)&(RD)[((size_t)r_ * 4 + p_) * 8];           \
    }                                                                       \
    _Pragma("unroll")                                                       \
    for (int nf = 0; nf < 2; ++nf) {                                        \
        int ch_ = wn * 32 + nf * 16 + l15 + lg * 64;                        \
        bf16x8 bw = *(const bf16x8*)&Bs[BSR][ch_][0];                       \
        _Pragma("unroll")                                                   \
        for (int f = 0; f < 3; ++f)                                         \
            acc[f][nf] = MFMA16(a_[f], bw, acc[f][nf]);                     \
    }                                                                       \
    if (HAS_W) {                                                            \
        uint2 u_;                                                           \
        u_.x = cvtpk(PACKV[0], PACKV[1]);                                   \
        u_.y = cvtpk(PACKV[2], PACKV[3]);                                   \
        *(uint2*)&Bs[BSW][bch][bhalf * 4] = u_;                             \
    }                                                                       \
    LGKMBAR;                                                                \
} while (0)

__global__ __launch_bounds__(512, 4) void ffn2(
    const unsigned short* __restrict__ Hbuf, const float* __restrict__ w2,
    const int* __restrict__ counts, const int* __restrict__ offsets,
    const float* __restrict__ row_gatew,
    float* __restrict__ OPa, float* __restrict__ OPb) {
    __shared__ __align__(16) unsigned short As[3 * ASZ];           // 36 KB
    __shared__ __align__(16) unsigned short Bs[2][256][8];         //  8 KB

    int bid = blockIdx.x;
    int e   = bid & 7;
    int idx = bid >> 3;                  // 0..63
    int d0 = (idx >> 1) * 64;
    int ks = idx & 1;                    // K-half
    int k0 = ks * (FF / 2);
    float* OP = ks ? OPb : OPa;

    int Me = counts[e];
    if (Me == 0) return;
    int off = offsets[e];

    int t = threadIdx.x;
    int lane = t & 63;
    int w = t >> 6;
    int wm = w >> 1, wn = w & 1;
    int l15 = lane & 15, lg = lane >> 4;

    const float* w2e = w2 + (size_t)e * FF * DIM + d0;

    // B role: half frag-chunk (4 k-strided fp32) per thread per epoch
    int bcol = t & 63, blg = (t >> 6) & 3, bhalf = t >> 8;
    const float* bsrc = w2e + (size_t)(k0 + blg * 8 + bhalf * 4) * DIM + bcol;
    int bch = bcol + blg * 64;

    const int NST = (FF / 2) / BKE;      // 64 epochs per K-half

    for (int mb = 0; mb < Me; mb += BM) {
        __syncthreads();
        const unsigned short* asrc0;
        const unsigned short* asrc1;
        {
            int m0 = t >> 2, c0 = t & 3;
            int rl0 = mb + m0;
            asrc0 = Hbuf + (size_t)(off + ((rl0 < Me) ? rl0 : (Me - 1))) * FF
                         + k0 + (((c0 - (m0 >> 1)) & 3) << 3);
            int i1 = 512 + t;
            int m1 = i1 >> 2, c1 = i1 & 3;
            int rl1 = mb + m1;
            asrc1 = Hbuf + (size_t)(off + ((rl1 < Me) ? rl1 : (Me - 1))) * FF
                         + k0 + (((c1 - (m1 >> 1)) & 3) << 3);
        }

        f32x4 acc[3][2];
#pragma unroll
        for (int f = 0; f < 3; ++f)
#pragma unroll
            for (int nf = 0; nf < 2; ++nf) acc[f][nf] = (f32x4){0.f, 0.f, 0.f, 0.f};

        unsigned short* pRd = As;
        unsigned short* pMd = As + ASZ;
        unsigned short* pWr = As + 2 * ASZ;

        float bX[4], bY[4];

        async16(&pRd[(size_t)t * 8], asrc0);
        if (t < 256) async16(&pRd[(size_t)(512 + t) * 8], asrc1);
        async16(&pMd[(size_t)t * 8], asrc0 + BKE);
        if (t < 256) async16(&pMd[(size_t)(512 + t) * 8], asrc1 + BKE);
        SCHEDBAR;
#pragma unroll
        for (int j = 0; j < 4; ++j) bX[j] = bsrc[(size_t)j * DIM];
        {
            uint2 u_;
            u_.x = cvtpk(bX[0], bX[1]);
            u_.y = cvtpk(bX[2], bX[3]);
            *(uint2*)&Bs[0][bch][bhalf * 4] = u_;
        }
#pragma unroll
        for (int j = 0; j < 4; ++j) bY[j] = bsrc[(size_t)(BKE + j) * DIM];
        LGKMBAR;

        for (int s = 0; s < NST - 2; s += 2) {
            EP2(pRd, pWr, 0, 1, bY, bX, s,     1, 1);
            EP2(pMd, pRd, 1, 0, bX, bY, s + 1, 1, 1);
            unsigned short* tt = pRd; pRd = pWr; pWr = pMd; pMd = tt;
        }
        EP2(pRd, pWr, 0, 1, bY, bX, NST - 2, 0, 1);
        EP2(pMd, pRd, 1, 0, bX, bY, NST - 1, 0, 0);

#pragma unroll
        for (int f = 0; f < 3; ++f)
#pragma unroll
            for (int nf = 0; nf < 2; ++nf)
#pragma unroll
                for (int r = 0; r < 4; ++r) {
                    int rl = mb + wm * 48 + f * 16 + lg * 4 + r;
                    if (rl < Me) {
                        int grow = off + rl;
                        float g = row_gatew[grow];
                        OP[(size_t)grow * DIM + d0 + wn * 32 + nf * 16 + l15] =
                            acc[f][nf][r] * g;
                    }
                }
    }
}

// ---------------------------------------------------------------------------
// Kernel 5: out[token] = OPa[p0]+OPb[p0] + OPa[p1]+OPb[p1]
// ---------------------------------------------------------------------------
__global__ void combine(const float* __restrict__ OPa, const float* __restrict__ OPb,
                        const int* __restrict__ pair_row, float* __restrict__ out) {
    int idx = blockIdx.x * blockDim.x + threadIdx.x;
    int token = idx >> 9;
    int q = idx & 511;
    int r0 = pair_row[token * 2 + 0];
    int r1 = pair_row[token * 2 + 1];
    float4 a0 = *(const float4*)(OPa + (size_t)r0 * DIM + q * 4);
    float4 b0 = *(const float4*)(OPb + (size_t)r0 * DIM + q * 4);
    float4 a1 = *(const float4*)(OPa + (size_t)r1 * DIM + q * 4);
    float4 b1 = *(const float4*)(OPb + (size_t)r1 * DIM + q * 4);
    float4 o;
    o.x = (a0.x + b0.x) + (a1.x + b1.x);
    o.y = (a0.y + b0.y) + (a1.y + b1.y);
    o.z = (a0.z + b0.z) + (a1.z + b1.z);
    o.w = (a0.w + b0.w) + (a1.w + b1.w);
    *(float4*)(out + (size_t)token * DIM + q * 4) = o;
}

// ---------------------------------------------------------------------------
extern "C" void kernel_launch(void* const* d_in, const int* in_sizes, int n_in,
                              void* d_out, int out_size, void* d_ws, size_t ws_size,
                              hipStream_t stream) {
    const float* x  = (const float*)d_in[0];
    const float* gw = (const float*)d_in[1];
    const float* w1 = (const float*)d_in[2];
    const float* w3 = (const float*)d_in[3];
    const float* w2 = (const float*)d_in[4];
    float* out = (float*)d_out;

    char* ws = (char*)d_ws;
    unsigned short* Hbuf = (unsigned short*)ws;                 //  8 MB bf16 [1024][4096]
    float* OPa           = (float*)(ws + 8388608);              //  8 MB f32  [1024][2048]
    unsigned short* xbf  = (unsigned short*)(ws + 16777216);    //  2 MB bf16 [512][2048]
    float* OPb           = (float*)(ws + 20971520);             //  8 MB f32  [1024][2048]
    char* meta           = ws + 29360128;
    int*   tok_expert = (int*)(meta);
    float* tok_gatew  = (float*)(meta + 4096);
    int*   counts     = (int*)(meta + 8192);
    int*   offsets    = (int*)(meta + 8224);
    int*   row_token  = (int*)(meta + 8256);
    float* row_gatew  = (float*)(meta + 12352);
    int*   pair_row   = (int*)(meta + 16448);

    gate_topk<<<TOK, 64, 0, stream>>>(x, gw, xbf, tok_expert, tok_gatew);
    build_lists<<<1, 512, 0, stream>>>(tok_expert, tok_gatew, counts, offsets,
                                       row_token, row_gatew, pair_row);
    ffn1<<<NE * 32, 1024, 0, stream>>>(xbf, w1, w3, counts, offsets, row_token, Hbuf);
    ffn2<<<NE * 64, 512, 0, stream>>>(Hbuf, w2, counts, offsets, row_gatew, OPa, OPb);
    combine<<<1024, 256, 0, stream>>>(OPa, OPb, pair_row, out);
}

// Round 18
// 198.214 us; speedup vs baseline: 1.2709x; 1.2709x over previous
//
#include <hip/hip_runtime.h>
#include <hip/hip_bf16.h>
#include <cstdint>
#include <cstddef>

// Problem constants
#define NB   64
#define NS   8
#define DIM  2048
#define FF   4096
#define NE   8
#define TOK  512            // NB*NS
#define NPAIR 1024          // TOK*2

// GEMM tiling
#define BM   192            // 4 M-waves x 48 rows
#define BKE  32             // K per epoch
#define ASZ  (BM * 4 * 8)   // shorts per A LDS buffer (12 KB)

typedef __attribute__((ext_vector_type(4))) float f32x4;
typedef __attribute__((ext_vector_type(8))) short bf16x8;

#define MFMA16(a, b, c) __builtin_amdgcn_mfma_f32_16x16x32_bf16((a), (b), (c), 0, 0, 0)
#define SCHEDBAR __builtin_amdgcn_sched_barrier(0)
// barrier draining LDS only — vmcnt prefetches stay in flight across it
#define LGKMBAR do { asm volatile("s_waitcnt lgkmcnt(0)" ::: "memory"); \
                     asm volatile("s_barrier" ::: "memory");            \
                     __builtin_amdgcn_sched_barrier(0); } while (0)

// round-half-up fp32 -> bf16 (0.5 ulp)
static __device__ __forceinline__ short f2bf(float f) {
    unsigned u = __builtin_bit_cast(unsigned, f);
    return (short)((u + 0x8000u) >> 16);
}
// packed fp32x2 -> bf16x2 (RNE), 1 instruction
static __device__ __forceinline__ unsigned cvtpk(float lo, float hi) {
    unsigned r;
    asm("v_cvt_pk_bf16_f32 %0, %1, %2" : "=v"(r) : "v"(lo), "v"(hi));
    return r;
}
static __device__ __forceinline__ bf16x8 pack8(const float* v) {
    uint4 u;
    u.x = cvtpk(v[0], v[1]); u.y = cvtpk(v[2], v[3]);
    u.z = cvtpk(v[4], v[5]); u.w = cvtpk(v[6], v[7]);
    return __builtin_bit_cast(bf16x8, u);
}

static __device__ __forceinline__ void async16(void* l, const void* g) {
    __builtin_amdgcn_global_load_lds(
        (const __attribute__((address_space(1))) void*)g,
        (__attribute__((address_space(3))) void*)l, 16, 0, 0);
}

// ---------------------------------------------------------------------------
// Kernel 1: gating + x -> bf16 preconvert.
// ---------------------------------------------------------------------------
__global__ void gate_topk(const float* __restrict__ x, const float* __restrict__ gw,
                          unsigned short* __restrict__ xbf,
                          int* __restrict__ tok_expert, float* __restrict__ tok_gatew) {
    int token = blockIdx.x;
    int lane  = threadIdx.x;
    const float* xr = x + (size_t)token * DIM;

    float acc[NE];
#pragma unroll
    for (int e = 0; e < NE; ++e) acc[e] = 0.f;

    for (int d0 = lane * 8; d0 < DIM; d0 += 64 * 8) {
        float4 xa = *(const float4*)(xr + d0);
        float4 xb = *(const float4*)(xr + d0 + 4);
        bf16x8 v;
        v[0] = f2bf(xa.x); v[1] = f2bf(xa.y); v[2] = f2bf(xa.z); v[3] = f2bf(xa.w);
        v[4] = f2bf(xb.x); v[5] = f2bf(xb.y); v[6] = f2bf(xb.z); v[7] = f2bf(xb.w);
        *(bf16x8*)(xbf + (size_t)token * DIM + d0) = v;
#pragma unroll
        for (int j = 0; j < 8; ++j) {
            float xv = (j < 4) ? ((const float*)&xa)[j] : ((const float*)&xb)[j - 4];
            const float4* g = (const float4*)(gw + (size_t)(d0 + j) * NE);
            float4 g0 = g[0], g1 = g[1];
            acc[0] += xv * g0.x; acc[1] += xv * g0.y;
            acc[2] += xv * g0.z; acc[3] += xv * g0.w;
            acc[4] += xv * g1.x; acc[5] += xv * g1.y;
            acc[6] += xv * g1.z; acc[7] += xv * g1.w;
        }
    }
#pragma unroll
    for (int off = 32; off >= 1; off >>= 1) {
#pragma unroll
        for (int e = 0; e < NE; ++e) acc[e] += __shfl_down(acc[e], off);
    }
    if (lane == 0) {
        float b1 = -1e30f, b2 = -1e30f; int i1 = 0, i2 = 0;
#pragma unroll
        for (int e = 0; e < NE; ++e) {
            float v = acc[e];
            if (v > b1) { b2 = b1; i2 = i1; b1 = v; i1 = e; }
            else if (v > b2) { b2 = v; i2 = e; }
        }
        float t = __expf(b2 - b1);
        tok_expert[token * 2 + 0] = i1;
        tok_expert[token * 2 + 1] = i2;
        tok_gatew[token * 2 + 0] = 1.f / (1.f + t);
        tok_gatew[token * 2 + 1] = t / (1.f + t);
    }
}

// ---------------------------------------------------------------------------
// Kernel 2: deterministic per-expert token lists
// ---------------------------------------------------------------------------
__global__ void build_lists(const int* __restrict__ tok_expert,
                            const float* __restrict__ tok_gatew,
                            int* __restrict__ counts, int* __restrict__ offsets,
                            int* __restrict__ row_token, float* __restrict__ row_gatew,
                            int* __restrict__ pair_row) {
    __shared__ int s_off[NE];
    __shared__ int s_cnt[NE];
    int e    = threadIdx.x >> 6;
    int lane = threadIdx.x & 63;
    unsigned long long lt = (1ull << lane) - 1ull;

    int cnt = 0;
    for (int base = 0; base < NPAIR; base += 64) {
        int id = tok_expert[base + lane];
        unsigned long long m = __ballot(id == e);
        cnt += __popcll(m);
    }
    if (lane == 0) s_cnt[e] = cnt;
    __syncthreads();
    if (threadIdx.x == 0) {
        int o = 0;
        for (int i = 0; i < NE; ++i) {
            int c = s_cnt[i];
            counts[i] = c; offsets[i] = o; s_off[i] = o; o += c;
        }
    }
    __syncthreads();

    int rbase = s_off[e];
    for (int base = 0; base < NPAIR; base += 64) {
        int entry = base + lane;
        int id = tok_expert[entry];
        bool match = (id == e);
        unsigned long long m = __ballot(match);
        int pre = __popcll(m & lt);
        if (match) {
            int row = rbase + pre;
            row_token[row] = entry >> 1;
            row_gatew[row] = tok_gatew[entry];
            pair_row[entry] = row;
        }
        rbase += __popcll(m);
    }
}

// ---------------------------------------------------------------------------
// Kernel 3 (= R13): H = silu(Xbf*w1) .* (Xbf*w3).
// grid = 256 (bid = tile*8 + e -> expert pinned to one XCD), 1024 thr =
// 4M x 4N waves, BN=128. A: DMA into TRIPLE-buffered LDS (distance-2);
// retirement implicit via next epoch's pack8(B) register wait. No explicit
// vmcnt; barrier = lgkm-drain only.
// ---------------------------------------------------------------------------
#define EP1(RD, WR, BSR, BSW, PACKV, LOADV, S, HAS_P, HAS_W) do {           \
    if (HAS_P) {                                                            \
        if (t < 768) async16(&(WR)[(size_t)t * 8], asrc0 + ((S) + 2) * BKE);\
    }                                                                       \
    SCHEDBAR;                                                               \
    if (HAS_P) {                                                            \
        _Pragma("unroll")                                                   \
        for (int j = 0; j < 8; ++j)                                         \
            LOADV[j] = bsrc[(size_t)(((S) + 2) * BKE + j) * FF];            \
    }                                                                       \
    SCHEDBAR;                                                               \
    bf16x8 a_[3];                                                           \
    _Pragma("unroll")                                                       \
    for (int f = 0; f < 3; ++f) {                                           \
        int r_ = wm * 48 + f * 16 + l15;                                    \
        int p_ = (lg + (r_ >> 1)) & 3;                                      \
        a_[f] = *(const bf16x8*)&(RD)[((size_t)r_ * 4 + p_) * 8];           \
    }                                                                       \
    _Pragma("unroll")                                                       \
    for (int nf = 0; nf < 2; ++nf) {                                        \
        int ch_ = wn * 32 + nf * 16 + l15 + lg * 128;                       \
        bf16x8 b1f = *(const bf16x8*)&Bs[BSR][0][ch_][0];                   \
        bf16x8 b3f = *(const bf16x8*)&Bs[BSR][1][ch_][0];                   \
        _Pragma("unroll")                                                   \
        for (int f = 0; f < 3; ++f) {                                       \
            acc1[f][nf] = MFMA16(a_[f], b1f, acc1[f][nf]);                  \
            acc3[f][nf] = MFMA16(a_[f], b3f, acc3[f][nf]);                  \
        }                                                                   \
    }                                                                       \
    if (HAS_W) {                                                            \
        bf16x8 wv = pack8(PACKV);                                           \
        *(bf16x8*)&Bs[BSW][bmat][bch][0] = wv;                              \
    }                                                                       \
    LGKMBAR;                                                                \
} while (0)

__global__ __launch_bounds__(1024, 4) void ffn1(
    const unsigned short* __restrict__ xbf, const float* __restrict__ w1,
    const float* __restrict__ w3,
    const int* __restrict__ counts, const int* __restrict__ offsets,
    const int* __restrict__ row_token, unsigned short* __restrict__ Hbuf) {
    __shared__ __align__(16) unsigned short As[3 * ASZ];           // 36 KB
    __shared__ __align__(16) unsigned short Bs[2][2][512][8];      // 32 KB

    int bid = blockIdx.x;
    int e  = bid & 7;                    // expert -> XCD (round-robin dispatch)
    int f0 = (bid >> 3) * 128;

    int Me = counts[e];
    if (Me == 0) return;
    int off = offsets[e];

    int t = threadIdx.x;
    int lane = t & 63;
    int w = t >> 6;
    int wm = w >> 2, wn = w & 3;         // 4 M-waves x 4 N-waves
    int l15 = lane & 15, lg = lane >> 4;

    const float* w1e = w1 + (size_t)e * DIM * FF + f0;
    const float* w3e = w3 + (size_t)e * DIM * FF + f0;

    int bmat = t >> 9;
    int bc   = t & 511;
    int bcol = bc & 127, blg = bc >> 7;
    const float* bsrc = (bmat ? w3e : w1e) + (size_t)(blg * 8) * FF + bcol;
    int bch = bcol + blg * 128;

    const int NST = DIM / BKE;           // 64 epochs

    for (int mb = 0; mb < Me; mb += BM) {
        __syncthreads();
        const unsigned short* asrc0 = xbf;
        {
            int m0 = t >> 2, c0 = t & 3;
            int rl0 = mb + m0;
            int tok0 = row_token[off + ((rl0 < Me) ? rl0 : (Me - 1))];
            asrc0 = xbf + (size_t)tok0 * DIM + (((c0 - (m0 >> 1)) & 3) << 3);
        }

        f32x4 acc1[3][2], acc3[3][2];
#pragma unroll
        for (int f = 0; f < 3; ++f)
#pragma unroll
            for (int nf = 0; nf < 2; ++nf) {
                acc1[f][nf] = (f32x4){0.f, 0.f, 0.f, 0.f};
                acc3[f][nf] = (f32x4){0.f, 0.f, 0.f, 0.f};
            }

        unsigned short* pRd = As;
        unsigned short* pMd = As + ASZ;
        unsigned short* pWr = As + 2 * ASZ;

        float bX[8], bY[8];

        if (t < 768) {
            async16(&pRd[(size_t)t * 8], asrc0);
            async16(&pMd[(size_t)t * 8], asrc0 + BKE);
        }
        SCHEDBAR;
#pragma unroll
        for (int j = 0; j < 8; ++j) bX[j] = bsrc[(size_t)j * FF];
        {
            bf16x8 wv = pack8(bX);
            *(bf16x8*)&Bs[0][bmat][bch][0] = wv;
        }
#pragma unroll
        for (int j = 0; j < 8; ++j) bY[j] = bsrc[(size_t)(BKE + j) * FF];
        LGKMBAR;

        for (int s = 0; s < NST - 2; s += 2) {
            EP1(pRd, pWr, 0, 1, bY, bX, s,     1, 1);
            EP1(pMd, pRd, 1, 0, bX, bY, s + 1, 1, 1);
            unsigned short* tt = pRd; pRd = pWr; pWr = pMd; pMd = tt;
        }
        EP1(pRd, pWr, 0, 1, bY, bX, NST - 2, 0, 1);
        EP1(pMd, pRd, 1, 0, bX, bY, NST - 1, 0, 0);

#pragma unroll
        for (int f = 0; f < 3; ++f)
#pragma unroll
            for (int nf = 0; nf < 2; ++nf)
#pragma unroll
                for (int r = 0; r < 4; ++r) {
                    int rl = mb + wm * 48 + f * 16 + lg * 4 + r;
                    if (rl < Me) {
                        float a1 = acc1[f][nf][r], a3 = acc3[f][nf][r];
                        float h = (a1 / (1.f + __expf(-a1))) * a3;
                        Hbuf[(size_t)(off + rl) * FF + f0 + wn * 32 + nf * 16 + l15] =
                            (unsigned short)f2bf(h);
                    }
                }
    }
}

// ---------------------------------------------------------------------------
// Kernel 4 (= R14): OutPair partial = (H @ w2[K-half]) * gate_weight.
// K-SPLIT x2: grid = 512 (bid = (tile*2+ks)*8 + e), 2 blocks/CU -> barrier
// stalls of one block overlap with the co-resident block. Each block streams
// its w2 K-half exactly once (no duplicated B traffic). Partials -> OPa/OPb.
// ---------------------------------------------------------------------------
#define EP2(RD, WR, BSR, BSW, PACKV, LOADV, S, HAS_P, HAS_W) do {           \
    if (HAS_P) {                                                            \
        async16(&(WR)[(size_t)t * 8], asrc0 + ((S) + 2) * BKE);             \
        if (t < 256)                                                        \
            async16(&(WR)[(size_t)(512 + t) * 8], asrc1 + ((S) + 2) * BKE); \
    }                                                                       \
    SCHEDBAR;                                                               \
    if (HAS_P) {                                                            \
        _Pragma("unroll")                                                   \
        for (int j = 0; j < 4; ++j)                                         \
            LOADV[j] = bsrc[(size_t)(((S) + 2) * BKE + j) * DIM];           \
    }                                                                       \
    SCHEDBAR;                                                               \
    bf16x8 a_[3];                                                           \
    _Pragma("unroll")                                                       \
    for (int f = 0; f < 3; ++f) {                                           \
        int r_ = wm * 48 + f * 16 + l15;                                    \
        int p_ = (lg + (r_ >> 1)) & 3;                                      \
        a_[f] = *(const bf16x8*)&(RD)[((size_t)r_ * 4 + p_) * 8];           \
    }                                                                       \
    _Pragma("unroll")                                                       \
    for (int nf = 0; nf < 2; ++nf) {                                        \
        int ch_ = wn * 32 + nf * 16 + l15 + lg * 64;                        \
        bf16x8 bw = *(const bf16x8*)&Bs[BSR][ch_][0];                       \
        _Pragma("unroll")                                                   \
        for (int f = 0; f < 3; ++f)                                         \
            acc[f][nf] = MFMA16(a_[f], bw, acc[f][nf]);                     \
    }                                                                       \
    if (HAS_W) {                                                            \
        uint2 u_;                                                           \
        u_.x = cvtpk(PACKV[0], PACKV[1]);                                   \
        u_.y = cvtpk(PACKV[2], PACKV[3]);                                   \
        *(uint2*)&Bs[BSW][bch][bhalf * 4] = u_;                             \
    }                                                                       \
    LGKMBAR;                                                                \
} while (0)

__global__ __launch_bounds__(512, 4) void ffn2(
    const unsigned short* __restrict__ Hbuf, const float* __restrict__ w2,
    const int* __restrict__ counts, const int* __restrict__ offsets,
    const float* __restrict__ row_gatew,
    float* __restrict__ OPa, float* __restrict__ OPb) {
    __shared__ __align__(16) unsigned short As[3 * ASZ];           // 36 KB
    __shared__ __align__(16) unsigned short Bs[2][256][8];         //  8 KB

    int bid = blockIdx.x;
    int e   = bid & 7;
    int idx = bid >> 3;                  // 0..63
    int d0 = (idx >> 1) * 64;
    int ks = idx & 1;                    // K-half
    int k0 = ks * (FF / 2);
    float* OP = ks ? OPb : OPa;

    int Me = counts[e];
    if (Me == 0) return;
    int off = offsets[e];

    int t = threadIdx.x;
    int lane = t & 63;
    int w = t >> 6;
    int wm = w >> 1, wn = w & 1;
    int l15 = lane & 15, lg = lane >> 4;

    const float* w2e = w2 + (size_t)e * FF * DIM + d0;

    // B role: half frag-chunk (4 k-strided fp32) per thread per epoch
    int bcol = t & 63, blg = (t >> 6) & 3, bhalf = t >> 8;
    const float* bsrc = w2e + (size_t)(k0 + blg * 8 + bhalf * 4) * DIM + bcol;
    int bch = bcol + blg * 64;

    const int NST = (FF / 2) / BKE;      // 64 epochs per K-half

    for (int mb = 0; mb < Me; mb += BM) {
        __syncthreads();
        const unsigned short* asrc0;
        const unsigned short* asrc1;
        {
            int m0 = t >> 2, c0 = t & 3;
            int rl0 = mb + m0;
            asrc0 = Hbuf + (size_t)(off + ((rl0 < Me) ? rl0 : (Me - 1))) * FF
                         + k0 + (((c0 - (m0 >> 1)) & 3) << 3);
            int i1 = 512 + t;
            int m1 = i1 >> 2, c1 = i1 & 3;
            int rl1 = mb + m1;
            asrc1 = Hbuf + (size_t)(off + ((rl1 < Me) ? rl1 : (Me - 1))) * FF
                         + k0 + (((c1 - (m1 >> 1)) & 3) << 3);
        }

        f32x4 acc[3][2];
#pragma unroll
        for (int f = 0; f < 3; ++f)
#pragma unroll
            for (int nf = 0; nf < 2; ++nf) acc[f][nf] = (f32x4){0.f, 0.f, 0.f, 0.f};

        unsigned short* pRd = As;
        unsigned short* pMd = As + ASZ;
        unsigned short* pWr = As + 2 * ASZ;

        float bX[4], bY[4];

        async16(&pRd[(size_t)t * 8], asrc0);
        if (t < 256) async16(&pRd[(size_t)(512 + t) * 8], asrc1);
        async16(&pMd[(size_t)t * 8], asrc0 + BKE);
        if (t < 256) async16(&pMd[(size_t)(512 + t) * 8], asrc1 + BKE);
        SCHEDBAR;
#pragma unroll
        for (int j = 0; j < 4; ++j) bX[j] = bsrc[(size_t)j * DIM];
        {
            uint2 u_;
            u_.x = cvtpk(bX[0], bX[1]);
            u_.y = cvtpk(bX[2], bX[3]);
            *(uint2*)&Bs[0][bch][bhalf * 4] = u_;
        }
#pragma unroll
        for (int j = 0; j < 4; ++j) bY[j] = bsrc[(size_t)(BKE + j) * DIM];
        LGKMBAR;

        for (int s = 0; s < NST - 2; s += 2) {
            EP2(pRd, pWr, 0, 1, bY, bX, s,     1, 1);
            EP2(pMd, pRd, 1, 0, bX, bY, s + 1, 1, 1);
            unsigned short* tt = pRd; pRd = pWr; pWr = pMd; pMd = tt;
        }
        EP2(pRd, pWr, 0, 1, bY, bX, NST - 2, 0, 1);
        EP2(pMd, pRd, 1, 0, bX, bY, NST - 1, 0, 0);

#pragma unroll
        for (int f = 0; f < 3; ++f)
#pragma unroll
            for (int nf = 0; nf < 2; ++nf)
#pragma unroll
                for (int r = 0; r < 4; ++r) {
                    int rl = mb + wm * 48 + f * 16 + lg * 4 + r;
                    if (rl < Me) {
                        int grow = off + rl;
                        float g = row_gatew[grow];
                        OP[(size_t)grow * DIM + d0 + wn * 32 + nf * 16 + l15] =
                            acc[f][nf][r] * g;
                    }
                }
    }
}

// ---------------------------------------------------------------------------
// Kernel 5: out[token] = OPa[p0]+OPb[p0] + OPa[p1]+OPb[p1]
// ---------------------------------------------------------------------------
__global__ void combine(const float* __restrict__ OPa, const float* __restrict__ OPb,
                        const int* __restrict__ pair_row, float* __restrict__ out) {
    int idx = blockIdx.x * blockDim.x + threadIdx.x;
    int token = idx >> 9;
    int q = idx & 511;
    int r0 = pair_row[token * 2 + 0];
    int r1 = pair_row[token * 2 + 1];
    float4 a0 = *(const float4*)(OPa + (size_t)r0 * DIM + q * 4);
    float4 b0 = *(const float4*)(OPb + (size_t)r0 * DIM + q * 4);
    float4 a1 = *(const float4*)(OPa + (size_t)r1 * DIM + q * 4);
    float4 b1 = *(const float4*)(OPb + (size_t)r1 * DIM + q * 4);
    float4 o;
    o.x = (a0.x + b0.x) + (a1.x + b1.x);
    o.y = (a0.y + b0.y) + (a1.y + b1.y);
    o.z = (a0.z + b0.z) + (a1.z + b1.z);
    o.w = (a0.w + b0.w) + (a1.w + b1.w);
    *(float4*)(out + (size_t)token * DIM + q * 4) = o;
}

// ---------------------------------------------------------------------------
extern "C" void kernel_launch(void* const* d_in, const int* in_sizes, int n_in,
                              void* d_out, int out_size, void* d_ws, size_t ws_size,
                              hipStream_t stream) {
    const float* x  = (const float*)d_in[0];
    const float* gw = (const float*)d_in[1];
    const float* w1 = (const float*)d_in[2];
    const float* w3 = (const float*)d_in[3];
    const float* w2 = (const float*)d_in[4];
    float* out = (float*)d_out;

    char* ws = (char*)d_ws;
    unsigned short* Hbuf = (unsigned short*)ws;                 //  8 MB bf16 [1024][4096]
    float* OPa           = (float*)(ws + 8388608);              //  8 MB f32  [1024][2048]
    unsigned short* xbf  = (unsigned short*)(ws + 16777216);    //  2 MB bf16 [512][2048]
    float* OPb           = (float*)(ws + 20971520);             //  8 MB f32  [1024][2048]
    char* meta           = ws + 29360128;
    int*   tok_expert = (int*)(meta);
    float* tok_gatew  = (float*)(meta + 4096);
    int*   counts     = (int*)(meta + 8192);
    int*   offsets    = (int*)(meta + 8224);
    int*   row_token  = (int*)(meta + 8256);
    float* row_gatew  = (float*)(meta + 12352);
    int*   pair_row   = (int*)(meta + 16448);

    gate_topk<<<TOK, 64, 0, stream>>>(x, gw, xbf, tok_expert, tok_gatew);
    build_lists<<<1, 512, 0, stream>>>(tok_expert, tok_gatew, counts, offsets,
                                       row_token, row_gatew, pair_row);
    ffn1<<<NE * 32, 1024, 0, stream>>>(xbf, w1, w3, counts, offsets, row_token, Hbuf);
    ffn2<<<NE * 64, 512, 0, stream>>>(Hbuf, w2, counts, offsets, row_gatew, OPa, OPb);
    combine<<<1024, 256, 0, stream>>>(OPa, OPb, pair_row, out);
}